// Round 1
// baseline (255.796 us; speedup 1.0000x reference)
//
#include <hip/hip_runtime.h>
#include <math.h>

// mask[i][j] = (j < blk_end(i)) && (j != i),  blk_end = (i/n_nodes + 1)*n_nodes
// (equivalent to reference's ((i>j) | same_block) & (i!=j))
//
// Pure HBM-write-bound: n=8192 -> 268 MB fp32 out, ~0 bytes read.
// R5: 4x float4 per thread (64 B/thread), plain stores (NO nt — nt was the
// confound in R3/R4's regressions, not the loop). 16 KB per block, grid
// (n/4096, n). Goal: feed the VMEM write queue with 4 independent wide
// stores per wave and cut block churn 65536 -> 16384 blocks.

__global__ void __launch_bounds__(256)
Create_Mask_23871428231714_kernel(const int* __restrict__ n_nodes_p,
                                  float* __restrict__ out, int n) {
    const int n_nodes = *n_nodes_p;                 // scalar, s_load + L2 hit
    const int i = blockIdx.y;                       // row

    // blk_end = (i/n_nodes + 1) * n_nodes; pow2 fast path (n_nodes=64)
    int blk_end;
    if ((n_nodes & (n_nodes - 1)) == 0) {
        const int s = __ffs(n_nodes) - 1;
        blk_end = ((i >> s) + 1) << s;
    } else {
        blk_end = (i / n_nodes + 1) * n_nodes;
    }

    const size_t row = (size_t)i * (size_t)n;
    const int base = blockIdx.x * 4096;             // 4096 floats per block
    const int t4   = threadIdx.x << 2;              // thread's 16B slot

    // 4 independent chunks, each a fully-coalesced 1 KB/wave store.
    // Compute all four values first, then store — lets the compiler issue
    // the 4 global_store_dwordx4 back-to-back (ILP in the VMEM queue).
    float4 v[4];
    int    j[4];
    #pragma unroll
    for (int c = 0; c < 4; ++c) {
        const int j0 = base + c * 1024 + t4;
        j[c] = j0;
        v[c].x = ((j0     < blk_end) && (j0     != i)) ? 1.0f : 0.0f;
        v[c].y = ((j0 + 1 < blk_end) && (j0 + 1 != i)) ? 1.0f : 0.0f;
        v[c].z = ((j0 + 2 < blk_end) && (j0 + 2 != i)) ? 1.0f : 0.0f;
        v[c].w = ((j0 + 3 < blk_end) && (j0 + 3 != i)) ? 1.0f : 0.0f;
    }
    #pragma unroll
    for (int c = 0; c < 4; ++c) {
        if (j[c] < n) {                             // n multiple of 4 -> safe
            *reinterpret_cast<float4*>(out + row + (size_t)j[c]) = v[c];
        }
    }
}

extern "C" void kernel_launch(void* const* d_in, const int* in_sizes, int n_in,
                              void* d_out, int out_size, void* d_ws, size_t ws_size,
                              hipStream_t stream) {
    (void)in_sizes; (void)n_in; (void)d_ws; (void)ws_size;
    const int* n_nodes_p = (const int*)d_in[0];
    float* out = (float*)d_out;

    // out is n x n -> recover n on host (no device readback; graph-capture safe)
    const int n = (int)llround(sqrt((double)out_size));

    const int block = 256;
    const int elems_per_block = block * 4 * 4;      // 4 float4 per thread
    dim3 grid((n + elems_per_block - 1) / elems_per_block, n, 1);
    Create_Mask_23871428231714_kernel<<<grid, dim3(block, 1, 1), 0, stream>>>(
        n_nodes_p, out, n);
}